// Round 2
// baseline (483.622 us; speedup 1.0000x reference)
//
#include <hip/hip_runtime.h>
#include <hip/hip_bf16.h>
#include <math.h>

#define IN_DIM  8192
#define OUT_DIM 8192
#define BATCH   8192

// GATE_COEFFS columns (g0,g1,g2,g3) per row i
__device__ __constant__ float GC0[16] = {0,0,0,0, 0,0,0,0, 1,1,1,1, 1,1,1,1};
__device__ __constant__ float GC1[16] = {0,0,1,1, 0,0,1,1, -1,-1,0,0, -1,-1,0,0};
__device__ __constant__ float GC2[16] = {0,0,0,0, 1,1,1,1, -1,-1,-1,-1, 0,0,0,0};
__device__ __constant__ float GC3[16] = {0,1,-1,0, -1,0,-2,-1, 1,2,0,1, 0,1,-1,0};

// Kernel 1: c[j] = softmax(weight[j,:]) @ GATE_COEFFS  -> float4 per column
__global__ __launch_bounds__(256) void compute_c_kernel(
    const float* __restrict__ weight, float4* __restrict__ c)
{
    int row = blockIdx.x * 256 + threadIdx.x;
    if (row >= OUT_DIM) return;
    const float* wr = weight + (size_t)row * 16;
    float v[16];
    float m = -1e30f;
#pragma unroll
    for (int i = 0; i < 16; ++i) { v[i] = wr[i]; m = fmaxf(m, v[i]); }
    float s = 0.f;
#pragma unroll
    for (int i = 0; i < 16; ++i) { v[i] = __expf(v[i] - m); s += v[i]; }
    float inv = 1.0f / s;
    float c0 = 0.f, c1 = 0.f, c2 = 0.f, c3 = 0.f;
#pragma unroll
    for (int i = 0; i < 16; ++i) {
        c0 = fmaf(v[i], GC0[i], c0);
        c1 = fmaf(v[i], GC1[i], c1);
        c2 = fmaf(v[i], GC2[i], c2);
        c3 = fmaf(v[i], GC3[i], c3);
    }
    c[row] = make_float4(c0 * inv, c1 * inv, c2 * inv, c3 * inv);
}

// Kernel 2: one block per batch row; x-row staged in LDS; 4 cols/thread/iter
__global__ __launch_bounds__(256) void gate_main_kernel(
    const float* __restrict__ x,
    const float4* __restrict__ c,
    const int4* __restrict__ ia4,
    const int4* __restrict__ ib4,
    float4* __restrict__ out)
{
    __shared__ float xrow[IN_DIM];          // 32 KB
    const int b = blockIdx.x;
    const float4* xr4 = (const float4*)(x + (size_t)b * IN_DIM);
    float4* xs4 = (float4*)xrow;
#pragma unroll
    for (int i = 0; i < IN_DIM / 4 / 256; ++i)      // 8 iters
        xs4[i * 256 + threadIdx.x] = xr4[i * 256 + threadIdx.x];
    __syncthreads();

    float4* orow = out + (size_t)b * (OUT_DIM / 4);
#pragma unroll
    for (int it = 0; it < OUT_DIM / 4 / 256; ++it) { // 8 iters
        int j4 = it * 256 + threadIdx.x;
        int4 ia = ia4[j4];
        int4 ib = ib4[j4];
        float4 cA = c[4 * j4 + 0];
        float4 cB = c[4 * j4 + 1];
        float4 cC = c[4 * j4 + 2];
        float4 cD = c[4 * j4 + 3];

        float a0 = xrow[ia.x], b0 = xrow[ib.x];
        float a1 = xrow[ia.y], b1 = xrow[ib.y];
        float a2 = xrow[ia.z], b2 = xrow[ib.z];
        float a3 = xrow[ia.w], b3 = xrow[ib.w];

        float4 o;
        o.x = fmaf(a0, fmaf(b0, cA.w, cA.y), fmaf(b0, cA.z, cA.x));
        o.y = fmaf(a1, fmaf(b1, cB.w, cB.y), fmaf(b1, cB.z, cB.x));
        o.z = fmaf(a2, fmaf(b2, cC.w, cC.y), fmaf(b2, cC.z, cC.x));
        o.w = fmaf(a3, fmaf(b3, cD.w, cD.y), fmaf(b3, cD.z, cD.x));
        orow[j4] = o;
    }
}

extern "C" void kernel_launch(void* const* d_in, const int* in_sizes, int n_in,
                              void* d_out, int out_size, void* d_ws, size_t ws_size,
                              hipStream_t stream) {
    const float* x      = (const float*)d_in[0];
    const float* weight = (const float*)d_in[1];
    const int*   idx_a  = (const int*)d_in[2];
    const int*   idx_b  = (const int*)d_in[3];
    float* out = (float*)d_out;

    float4* c = (float4*)d_ws;  // OUT_DIM float4 = 128 KB scratch

    compute_c_kernel<<<OUT_DIM / 256, 256, 0, stream>>>(weight, c);
    gate_main_kernel<<<BATCH, 256, 0, stream>>>(
        x, c, (const int4*)idx_a, (const int4*)idx_b, (float4*)out);
}